// Round 1
// baseline (821.779 us; speedup 1.0000x reference)
//
#include <hip/hip_runtime.h>
#include <hip/hip_bf16.h>

// ---------- types / helpers ----------
typedef __attribute__((ext_vector_type(4))) float f32x4;
typedef __attribute__((ext_vector_type(8))) short s16x8;

__device__ __forceinline__ unsigned short f2b(float f) {
  unsigned int u = __float_as_uint(f);
  unsigned int r = (u + 0x7FFFu + ((u >> 16) & 1u)) >> 16;   // RNE f32->bf16
  return (unsigned short)r;
}
__device__ __forceinline__ float b2f(unsigned short h) {
  return __uint_as_float(((unsigned int)h) << 16);
}

enum { MODE_F32 = 0, MODE_VT = 1, MODE_Y = 2, MODE_SC = 3, MODE_CTX = 4 };
struct OutSpec { void* ptr; int mode; };
struct Outs5 { OutSpec o[5]; };
struct Ptr6 { const float* p[6]; };

// ---------- generic NT MFMA GEMM: C[m][n] = sum_k A[m][k]*B[n][k] (+bias)(+resid) ----------
// A: bf16 (or f32, converted during stage), row-major MxK. B: bf16 row-major NxK.
template<int BM, int BN, int WGM, int WGN, bool A_F32>
__global__ __launch_bounds__(256) void gemm_nt(
    const void* __restrict__ Aptr_, int lda, long long strideA,
    const unsigned short* __restrict__ Bptr_, int ldb, long long strideB,
    const float* __restrict__ biasBase, int biasStride, int perZ,
    Outs5 outs, const float* __restrict__ resid, int K)
{
  constexpr int BK = 32;
  constexpr int WM = BM / WGM, WN = BN / WGN;
  constexpr int WR = WM / 16, WC = WN / 16;
  __shared__ unsigned short lds_a[BM * BK];
  __shared__ unsigned short lds_b[BN * BK];
  const int z = blockIdx.z;
  const int tid = threadIdx.x;
  const int wave = tid >> 6, lane = tid & 63;
  const int l16 = lane & 15, lhi = lane >> 4;
  const int wm = (wave / WGN) * WM, wn = (wave % WGN) * WN;
  const int m0 = blockIdx.x * BM, n0 = blockIdx.y * BN;
  const unsigned short* Bp = Bptr_ + (long long)z * strideB;

  f32x4 acc[WR][WC];
  for (int r = 0; r < WR; ++r)
    for (int c = 0; c < WC; ++c) { f32x4 zz = {0.f, 0.f, 0.f, 0.f}; acc[r][c] = zz; }

  for (int k0 = 0; k0 < K; k0 += BK) {
    if constexpr (A_F32) {
      const float* Ap = (const float*)Aptr_ + (long long)z * strideA;
#pragma unroll
      for (int p = 0; p < BM / 32; ++p) {
        int t = p * 256 + tid;
        int row = t >> 3, cg = t & 7;                       // 8 float4 chunks per 32-float row
        f32x4 v = *(const f32x4*)(Ap + (long long)(m0 + row) * lda + k0 + cg * 4);
        unsigned short* d = &lds_a[row * BK + cg * 4];
        d[0] = f2b(v.x); d[1] = f2b(v.y); d[2] = f2b(v.z); d[3] = f2b(v.w);
      }
    } else {
      const unsigned short* Ap = (const unsigned short*)Aptr_ + (long long)z * strideA;
#pragma unroll
      for (int p = 0; p < BM / 64; ++p) {
        int t = p * 256 + tid;
        int row = t >> 2, cg = t & 3;                       // 4 16B chunks per 32-bf16 row
        *(int4*)&lds_a[row * BK + cg * 8] =
            *(const int4*)(Ap + (long long)(m0 + row) * lda + k0 + cg * 8);
      }
    }
#pragma unroll
    for (int p = 0; p < BN / 64; ++p) {
      int t = p * 256 + tid;
      int row = t >> 2, cg = t & 3;
      *(int4*)&lds_b[row * BK + cg * 8] =
          *(const int4*)(Bp + (long long)(n0 + row) * ldb + k0 + cg * 8);
    }
    __syncthreads();
    s16x8 af[WR], bfv[WC];
#pragma unroll
    for (int r = 0; r < WR; ++r)
      af[r] = *(const s16x8*)&lds_a[(wm + r * 16 + l16) * BK + lhi * 8];
#pragma unroll
    for (int c = 0; c < WC; ++c)
      bfv[c] = *(const s16x8*)&lds_b[(wn + c * 16 + l16) * BK + lhi * 8];
#pragma unroll
    for (int r = 0; r < WR; ++r)
#pragma unroll
      for (int c = 0; c < WC; ++c)
        acc[r][c] = __builtin_amdgcn_mfma_f32_16x16x32_bf16(af[r], bfv[c], acc[r][c], 0, 0, 0);
    __syncthreads();
  }

  OutSpec spec = perZ ? outs.o[z] : outs.o[0];
  const float* bias = biasBase ? (biasBase + (long long)z * biasStride) : nullptr;
#pragma unroll
  for (int r = 0; r < WR; ++r) {
#pragma unroll
    for (int c = 0; c < WC; ++c) {
      int n = n0 + wn + c * 16 + l16;
      int rb = m0 + wm + r * 16 + lhi * 4;
      float bv = bias ? bias[n] : 0.f;
#pragma unroll
      for (int j = 0; j < 4; ++j) {
        int m = rb + j;
        float v = acc[r][c][j] + bv;
        if (spec.mode == MODE_F32) {
          ((float*)spec.ptr)[(long long)m * 512 + n] = v;
        } else if (spec.mode == MODE_VT) {               // V^T: (B,H,HD,S) bf16
          int b = m >> 9, s = m & 511;
          ((unsigned short*)spec.ptr)[(((long long)(b * 8 + (n >> 6))) * 64 + (n & 63)) * 512 + s] = f2b(v);
        } else if (spec.mode == MODE_Y) {                // y = c + bias + resid
          ((float*)spec.ptr)[(long long)m * 512 + n] = v + resid[(long long)m * 512 + n];
        } else if (spec.mode == MODE_SC) {               // bf16 scores, batched by z
          ((unsigned short*)spec.ptr)[(long long)z * 262144 + m * 512 + n] = f2b(v);
        } else {                                         // MODE_CTX: (B,S,D) bf16 from (b,h)
          int b = z >> 3, h = z & 7;
          ((unsigned short*)spec.ptr)[((long long)(b * 512 + m)) * 512 + h * 64 + n] = f2b(v);
        }
      }
    }
  }
}

// ---------- weight transpose: Wt[l][mat][n][k] = bf16(W[l][k][n]) ----------
__global__ __launch_bounds__(256) void wt_k(Ptr6 srcs, unsigned short* __restrict__ wt) {
  __shared__ float tile[32][33];
  int zz = blockIdx.z;                    // zz = l*6 + mat
  int l = zz / 6, mat = zz % 6;
  const float* src = srcs.p[mat] + (long long)l * 262144;
  int tx = threadIdx.x, ty = threadIdx.y; // (32,8)
  int n0 = blockIdx.x * 32, k0 = blockIdx.y * 32;
#pragma unroll
  for (int r = 0; r < 4; ++r)
    tile[ty + r * 8][tx] = src[(long long)(k0 + ty + r * 8) * 512 + n0 + tx];
  __syncthreads();
#pragma unroll
  for (int r = 0; r < 4; ++r)
    wt[(long long)zz * 262144 + (long long)(n0 + ty + r * 8) * 512 + k0 + tx] =
        f2b(tile[tx][ty + r * 8]);
}

// ---------- bias packing + fused quantum matrices Ar=qwr@em, Ai=qwi@em ----------
__global__ __launch_bounds__(256) void prep_k(Ptr6 biases,
    const float* __restrict__ qwr, const float* __restrict__ qwi, const float* __restrict__ qem,
    const float* __restrict__ kwr, const float* __restrict__ kwi, const float* __restrict__ kem,
    float* __restrict__ biasPacked, float* __restrict__ ArAi) {
  int l = blockIdx.x, t = threadIdx.x;
  for (int m = 0; m < 6; ++m)
    for (int d = t; d < 512; d += 256)
      biasPacked[(l * 6 + m) * 512 + d] = biases.p[m][l * 512 + d];
  int i = t >> 4, j = t & 15;
  const float* em0 = qem + l * 256;
  float ar = 0.f, ai = 0.f;
  for (int tt = 0; tt < 16; ++tt) {
    ar += qwr[l * 256 + i * 16 + tt] * em0[tt * 16 + j];
    ai += qwi[l * 256 + i * 16 + tt] * em0[tt * 16 + j];
  }
  ArAi[(l * 4 + 0) * 256 + t] = ar;
  ArAi[(l * 4 + 1) * 256 + t] = ai;
  const float* em1 = kem + l * 256;
  ar = 0.f; ai = 0.f;
  for (int tt = 0; tt < 16; ++tt) {
    ar += kwr[l * 256 + i * 16 + tt] * em1[tt * 16 + j];
    ai += kwi[l * 256 + i * 16 + tt] * em1[tt * 16 + j];
  }
  ArAi[(l * 4 + 2) * 256 + t] = ar;
  ArAi[(l * 4 + 3) * 256 + t] = ai;
}

// ---------- visual projection partials + final proj sum ----------
__global__ __launch_bounds__(512) void vispart_k(const float* __restrict__ vis,
    const float* __restrict__ Wvis, float* __restrict__ part) {
  int b = blockIdx.x, chunk = blockIdx.y, d = threadIdx.x;
  float acc = 0.f;
  for (int k = chunk * 64; k < chunk * 64 + 64; ++k)
    acc += vis[b * 2048 + k] * Wvis[(long long)k * 512 + d];
  part[(b * 32 + chunk) * 512 + d] = acc;
}
__global__ __launch_bounds__(512) void projsum_k(const float* __restrict__ part,
    const float* __restrict__ bvis, const float* __restrict__ temporal,
    const float* __restrict__ Wtemp, const float* __restrict__ btemp, float* __restrict__ proj) {
  int b = blockIdx.x, d = threadIdx.x;
  float acc = bvis[d] + btemp[d];
  for (int c = 0; c < 32; ++c) acc += part[(b * 32 + c) * 512 + d];
  for (int k = 0; k < 64; ++k) acc += temporal[b * 64 + k] * Wtemp[k * 512 + d];
  proj[b * 512 + d] = acc;
}

// ---------- embedding + positional encoding ----------
__global__ __launch_bounds__(512) void embed_k(const int* __restrict__ text,
    const float* __restrict__ emb, const float* __restrict__ proj,
    float* __restrict__ x, unsigned short* __restrict__ xb) {
  int row = blockIdx.x;
  int b = row >> 9, s = row & 511;
  int d = threadIdx.x;
  int tok = text[row];
  float v = emb[(long long)tok * 512 + d] + proj[b * 512 + d];
  float fr = __expf((float)((d >> 1) << 1) * (-9.2103403719761836f / 512.f));
  float ang = (float)s * fr;
  v += (d & 1) ? cosf(ang) : sinf(ang);
  x[(long long)row * 512 + d] = v;
  xb[(long long)row * 512 + d] = f2b(v);
}

// ---------- quantum branch: qs = x@sg; probs = (qs@Ar)^2 + (qs@Ai)^2; fw ----------
__global__ __launch_bounds__(64) void quantum_k(const float* __restrict__ x,
    const float* __restrict__ sg_q, const float* __restrict__ sg_k,
    const float* __restrict__ ArAiL, float* __restrict__ qp, float* __restrict__ kp,
    float* __restrict__ fwq, float* __restrict__ fwk) {
  __shared__ float red[64][17];
  __shared__ float qs[16];
  __shared__ float pv[16];
  int row = blockIdx.x, side = blockIdx.y, lane = threadIdx.x;
  const float* sg = side ? sg_k : sg_q;
  const float* Ar = ArAiL + side * 512;
  const float* Ai = Ar + 256;
  float acc[16];
#pragma unroll
  for (int j = 0; j < 16; ++j) acc[j] = 0.f;
  for (int kk = 0; kk < 8; ++kk) {
    int k = kk * 64 + lane;
    float xv = x[(long long)row * 512 + k];
    const float* sgr = sg + k * 16;
#pragma unroll
    for (int j = 0; j < 16; ++j) acc[j] += xv * sgr[j];
  }
#pragma unroll
  for (int j = 0; j < 16; ++j) red[lane][j] = acc[j];
  __syncthreads();
  if (lane < 16) {
    float s = 0.f;
    for (int t = 0; t < 64; ++t) s += red[t][lane];
    qs[lane] = s;
  }
  __syncthreads();
  if (lane < 16) {
    float tr = 0.f, ti = 0.f;
    for (int t = 0; t < 16; ++t) {
      float q = qs[t];
      tr += q * Ar[t * 16 + lane];
      ti += q * Ai[t * 16 + lane];
    }
    float p = tr * tr + ti * ti;
    (side ? kp : qp)[row * 16 + lane] = p;
    pv[lane] = p;
  }
  __syncthreads();
  if (lane == 0) {
    float s = 0.f;
    for (int j = 0; j < 16; ++j) s += pv[j];
    (side ? fwk : fwq)[row] = 1.f / (1.f + __expf(-s * (1.f / 16.f)));
  }
}

// ---------- fuse: ext[b,h,i,0:64]=sA*(0.7*lin+0.3*(fw*probs@mb+(1-fw)*tanh(cl))); [64:80]=sB*qp; [80:96]=0 ----------
__global__ __launch_bounds__(512) void fuse_k(const float* __restrict__ lin,
    const float* __restrict__ cl, const float* __restrict__ qp, const float* __restrict__ fw,
    const float* __restrict__ mb, unsigned short* __restrict__ ext, float sA, float sB) {
  int row = blockIdx.x;
  int b = row >> 9, i = row & 511;
  int d = threadIdx.x;
  const float* qpr = qp + row * 16;
  float fwv = fw[row];
  float qout = 0.f;
#pragma unroll
  for (int t = 0; t < 16; ++t) qout += qpr[t] * mb[t * 512 + d];
  float qq = fwv * qout + (1.f - fwv) * tanhf(cl[(long long)row * 512 + d]);
  float val = (0.7f * lin[(long long)row * 512 + d] + 0.3f * qq) * sA;
  int h = d >> 6, dd = d & 63;
  ext[(((long long)(b * 8 + h)) * 512 + i) * 96 + dd] = f2b(val);
  if (d < 128) {
    int h2 = d >> 4, j = d & 15;
    ext[(((long long)(b * 8 + h2)) * 512 + i) * 96 + 64 + j] = f2b(sB * qpr[j]);
  } else if (d < 256) {
    int t2 = d - 128;
    int h2 = t2 >> 4, j = t2 & 15;
    ext[(((long long)(b * 8 + h2)) * 512 + i) * 96 + 80 + j] = 0;
  }
}

// ---------- row softmax: bf16 scores -> fp32 attn (d_out) ----------
__global__ __launch_bounds__(256) void softmax_k(const unsigned short* __restrict__ sc,
                                                 float* __restrict__ attn) {
  __shared__ float red[256];
  long long base = (long long)blockIdx.x * 512;
  int t = threadIdx.x;
  float v0 = b2f(sc[base + t]), v1 = b2f(sc[base + 256 + t]);
  red[t] = fmaxf(v0, v1);
  __syncthreads();
  for (int s = 128; s > 0; s >>= 1) { if (t < s) red[t] = fmaxf(red[t], red[t + s]); __syncthreads(); }
  float mx = red[0];
  __syncthreads();
  float e0 = __expf(v0 - mx), e1 = __expf(v1 - mx);
  red[t] = e0 + e1;
  __syncthreads();
  for (int s = 128; s > 0; s >>= 1) { if (t < s) red[t] += red[t + s]; __syncthreads(); }
  float inv = 1.f / red[0];
  attn[base + t] = e0 * inv;
  attn[base + 256 + t] = e1 * inv;
}

// ---------- layernorm ----------
__global__ __launch_bounds__(256) void ln_k(const float* __restrict__ y,
    const float* __restrict__ g, const float* __restrict__ be,
    float* __restrict__ xo, unsigned short* __restrict__ xb, float* __restrict__ xo2) {
  __shared__ float red[256];
  long long base = (long long)blockIdx.x * 512;
  int t = threadIdx.x;
  float a = y[base + t], b = y[base + 256 + t];
  red[t] = a + b;
  __syncthreads();
  for (int s = 128; s > 0; s >>= 1) { if (t < s) red[t] += red[t + s]; __syncthreads(); }
  float mu = red[0] * (1.f / 512.f);
  __syncthreads();
  float d0 = a - mu, d1 = b - mu;
  red[t] = d0 * d0 + d1 * d1;
  __syncthreads();
  for (int s = 128; s > 0; s >>= 1) { if (t < s) red[t] += red[t + s]; __syncthreads(); }
  float rstd = rsqrtf(red[0] * (1.f / 512.f) + 1e-5f);
  float o0 = d0 * rstd * g[t] + be[t];
  float o1 = d1 * rstd * g[t + 256] + be[t + 256];
  xo[base + t] = o0; xo[base + 256 + t] = o1;
  xb[base + t] = f2b(o0); xb[base + 256 + t] = f2b(o1);
  if (xo2) { xo2[base + t] = o0; xo2[base + 256 + t] = o1; }
}

// ---------- pooled heads ----------
__global__ __launch_bounds__(512) void head_k(const float* __restrict__ x,
    const float* __restrict__ Ws, const float* __restrict__ bs,
    const float* __restrict__ Wd, const float* __restrict__ bd,
    const float* __restrict__ We, const float* __restrict__ be, float* __restrict__ out) {
  __shared__ float pooled[512];
  __shared__ float dl[5];
  int b = blockIdx.x, d = threadIdx.x;
  float s = 0.f;
  for (int t = 0; t < 512; ++t) s += x[((long long)(b * 512 + t)) * 512 + d];
  pooled[d] = s * (1.f / 512.f);
  __syncthreads();
  if (d < 64) {
    float a = bs[d];
    for (int t = 0; t < 512; ++t) a += pooled[t] * Ws[t * 64 + d];
    out[b * 64 + d] = 1.f / (1.f + __expf(-a));
  } else if (d < 69) {
    int j = d - 64;
    float a = bd[j];
    for (int t = 0; t < 512; ++t) a += pooled[t] * Wd[t * 5 + j];
    dl[j] = a;
  } else if (d == 69) {
    float a = be[0];
    for (int t = 0; t < 512; ++t) a += pooled[t] * We[t];
    out[276 + b] = 1.f / (1.f + __expf(-a));
  }
  __syncthreads();
  if (d < 5) {
    float mx = dl[0];
    for (int j = 1; j < 5; ++j) mx = fmaxf(mx, dl[j]);
    float sm = 0.f;
    for (int j = 0; j < 5; ++j) sm += __expf(dl[j] - mx);
    out[256 + b * 5 + d] = __expf(dl[d] - mx) / sm;
  }
}

// ---------- host ----------
extern "C" void kernel_launch(void* const* d_in, const int* in_sizes, int n_in,
                              void* d_out, int out_size, void* d_ws, size_t ws_size,
                              hipStream_t stream) {
  (void)in_sizes; (void)n_in; (void)out_size; (void)ws_size;
  const int*   text     = (const int*)  d_in[0];
  const float* visual   = (const float*)d_in[1];
  const float* temporal = (const float*)d_in[2];
  const float* embedw   = (const float*)d_in[3];
  const float* Wvis  = (const float*)d_in[4];  const float* bvis  = (const float*)d_in[5];
  const float* Wtemp = (const float*)d_in[6];  const float* btemp = (const float*)d_in[7];
  const float* Wq = (const float*)d_in[8];   const float* bq = (const float*)d_in[9];
  const float* Wk = (const float*)d_in[10];  const float* bk = (const float*)d_in[11];
  const float* Wv = (const float*)d_in[12];  const float* bv = (const float*)d_in[13];
  const float* Wo = (const float*)d_in[14];  const float* bo = (const float*)d_in[15];
  const float* qW = (const float*)d_in[16];  const float* qb = (const float*)d_in[17];
  const float* q_qwr = (const float*)d_in[18]; const float* q_qwi = (const float*)d_in[19];
  const float* q_sg  = (const float*)d_in[20]; const float* q_em  = (const float*)d_in[21];
  const float* q_mb  = (const float*)d_in[22];
  const float* kW = (const float*)d_in[23];  const float* kb = (const float*)d_in[24];
  const float* k_qwr = (const float*)d_in[25]; const float* k_qwi = (const float*)d_in[26];
  const float* k_sg  = (const float*)d_in[27]; const float* k_em  = (const float*)d_in[28];
  const float* k_mb  = (const float*)d_in[29];
  const float* ln_g = (const float*)d_in[30]; const float* ln_b = (const float*)d_in[31];
  const float* Ws = (const float*)d_in[32];  const float* bs_ = (const float*)d_in[33];
  const float* Wd = (const float*)d_in[34];  const float* bd = (const float*)d_in[35];
  const float* We = (const float*)d_in[36];  const float* be = (const float*)d_in[37];
  float* out = (float*)d_out;

  char* w = (char*)d_ws;
  auto alloc = [&](size_t bytes) {
    char* p = w;
    w += (bytes + 255) & ~(size_t)255;
    return p;
  };
  float* ws_x   = (float*)alloc(2048ll * 512 * 4);
  unsigned short* ws_xb = (unsigned short*)alloc(2048ll * 512 * 2);
  unsigned short* ws_Wt = (unsigned short*)alloc(36ll * 262144 * 2);
  float* ws_bias = (float*)alloc(6ll * 6 * 512 * 4);
  float* ws_ArAi = (float*)alloc(6ll * 1024 * 4);
  float* ws_proj = (float*)alloc(4ll * 512 * 4);
  float* ws_vp   = (float*)alloc(4ll * 32 * 512 * 4);
  float* ws_Q    = (float*)alloc(2048ll * 512 * 4);   // reused as y later in the layer
  float* ws_K    = (float*)alloc(2048ll * 512 * 4);
  float* ws_Cq   = (float*)alloc(2048ll * 512 * 4);
  float* ws_Ck   = (float*)alloc(2048ll * 512 * 4);
  float* ws_qp   = (float*)alloc(2048ll * 16 * 4);
  float* ws_kp   = (float*)alloc(2048ll * 16 * 4);
  float* ws_fwq  = (float*)alloc(2048ll * 4);
  float* ws_fwk  = (float*)alloc(2048ll * 4);
  unsigned short* ws_Vt   = (unsigned short*)alloc(2048ll * 512 * 2);
  unsigned short* ws_Qext = (unsigned short*)alloc(4ll * 8 * 512 * 96 * 2);
  unsigned short* ws_Kext = (unsigned short*)alloc(4ll * 8 * 512 * 96 * 2);
  unsigned short* ws_sc   = (unsigned short*)alloc(4ll * 8 * 512 * 512 * 2);
  unsigned short* ws_ctx  = (unsigned short*)alloc(2048ll * 512 * 2);
  float* ws_y    = (float*)alloc(2048ll * 512 * 4);

  // preprocess (per call — deterministic)
  Ptr6 wsrc = {{Wq, Wk, Wv, qW, kW, Wo}};
  wt_k<<<dim3(16, 16, 36), dim3(32, 8), 0, stream>>>(wsrc, ws_Wt);
  Ptr6 bsrc = {{bq, bk, bv, qb, kb, bo}};
  prep_k<<<dim3(6), dim3(256), 0, stream>>>(bsrc, q_qwr, q_qwi, q_em, k_qwr, k_qwi, k_em,
                                            ws_bias, ws_ArAi);
  vispart_k<<<dim3(4, 32), dim3(512), 0, stream>>>(visual, Wvis, ws_vp);
  projsum_k<<<dim3(4), dim3(512), 0, stream>>>(ws_vp, bvis, temporal, Wtemp, btemp, ws_proj);
  embed_k<<<dim3(2048), dim3(512), 0, stream>>>(text, embedw, ws_proj, ws_x, ws_xb);

  const long long ATTN_OFF = 280ll + 1048576ll;  // skill(256)+diff(20)+eng(4)+x(1048576)
  for (int l = 0; l < 6; ++l) {
    const unsigned short* WtL = ws_Wt + (long long)l * 6 * 262144;
    const float* biasL = ws_bias + (long long)l * 6 * 512;

    // 5-way batched GEMM: Q, K, V(->Vt bf16), Cq, Ck
    Outs5 o5{};
    o5.o[0] = { ws_Q, MODE_F32 };  o5.o[1] = { ws_K, MODE_F32 };
    o5.o[2] = { ws_Vt, MODE_VT };  o5.o[3] = { ws_Cq, MODE_F32 };
    o5.o[4] = { ws_Ck, MODE_F32 };
    gemm_nt<128, 128, 2, 2, false><<<dim3(16, 4, 5), 256, 0, stream>>>(
        ws_xb, 512, 0ll, WtL, 512, 262144ll, biasL, 512, 1, o5, nullptr, 512);

    quantum_k<<<dim3(2048, 2), 64, 0, stream>>>(ws_x, q_sg + l * 8192, k_sg + l * 8192,
        ws_ArAi + l * 1024, ws_qp, ws_kp, ws_fwq, ws_fwk);

    // Qext gets 1/sqrt(64)=0.125 and the 0.1 interference scale folded in
    fuse_k<<<dim3(2048), dim3(512), 0, stream>>>(ws_Q, ws_Cq, ws_qp, ws_fwq,
        q_mb + l * 8192, ws_Qext, 0.125f, 0.1f);
    fuse_k<<<dim3(2048), dim3(512), 0, stream>>>(ws_K, ws_Ck, ws_kp, ws_fwk,
        k_mb + l * 8192, ws_Kext, 1.0f, 1.0f);

    // scores (K=96 includes interference block), bf16 out
    Outs5 osc{};
    osc.o[0] = { ws_sc, MODE_SC };
    gemm_nt<128, 128, 2, 2, false><<<dim3(4, 4, 32), 256, 0, stream>>>(
        ws_Qext, 96, 512ll * 96, ws_Kext, 96, 512ll * 96, nullptr, 0, 0, osc, nullptr, 96);

    float* attnL = out + ATTN_OFF + (long long)l * 8388608;
    softmax_k<<<dim3(16384), dim3(256), 0, stream>>>(ws_sc, attnL);

    // ctx = attn @ V  (A is fp32 attn from d_out, converted in stage)
    Outs5 octx{};
    octx.o[0] = { ws_ctx, MODE_CTX };
    gemm_nt<64, 64, 2, 2, true><<<dim3(8, 1, 32), 256, 0, stream>>>(
        attnL, 512, 262144ll, ws_Vt, 512, 32768ll, nullptr, 0, 0, octx, nullptr, 512);

    // y = ctx @ Wo + bo + x   (64x64 tile -> 256 blocks for occupancy)
    Outs5 oy{};
    oy.o[0] = { ws_y, MODE_Y };
    gemm_nt<64, 64, 2, 2, false><<<dim3(32, 8, 1), 256, 0, stream>>>(
        ws_ctx, 512, 0ll, WtL + 5 * 262144, 512, 0ll, biasL + 5 * 512, 0, 0, oy, ws_x, 512);

    ln_k<<<dim3(2048), dim3(256), 0, stream>>>(ws_y, ln_g + l * 512, ln_b + l * 512,
        ws_x, ws_xb, (l == 5) ? (out + 280) : nullptr);
  }

  head_k<<<dim3(4), dim3(512), 0, stream>>>(ws_x, Ws, bs_, Wd, bd, We, be, out);
}

// Round 2
// 621.312 us; speedup vs baseline: 1.3226x; 1.3226x over previous
//
#include <hip/hip_runtime.h>
#include <hip/hip_bf16.h>

// ---------- types / helpers ----------
typedef __attribute__((ext_vector_type(4))) float f32x4;
typedef __attribute__((ext_vector_type(8))) short s16x8;

__device__ __forceinline__ unsigned short f2b(float f) {
  unsigned int u = __float_as_uint(f);
  unsigned int r = (u + 0x7FFFu + ((u >> 16) & 1u)) >> 16;   // RNE f32->bf16
  return (unsigned short)r;
}
__device__ __forceinline__ float b2f(unsigned short h) {
  return __uint_as_float(((unsigned int)h) << 16);
}
__device__ __forceinline__ void gload16(const void* g, void* l) {
  __builtin_amdgcn_global_load_lds(
      (const __attribute__((address_space(1))) void*)g,
      (__attribute__((address_space(3))) void*)l, 16, 0, 0);
}

enum { MODE_F32 = 0, MODE_VT = 1, MODE_Y = 2, MODE_SC = 3, MODE_CTX = 4 };
struct OutSpec { void* ptr; int mode; };
struct Outs5 { OutSpec o[5]; };
struct Ptr6 { const float* p[6]; };

// ---------- generic NT MFMA GEMM: C[m][n] = sum_k A[m][k]*B[n][k] (+bias)(+resid) ----------
// A,B bf16 row-major (MxK / NxK). Double-buffered LDS, global_load_lds x16 staging.
template<int BM, int BN, int WGM, int WGN>
__global__ __launch_bounds__(256) void gemm_nt(
    const unsigned short* __restrict__ A, int lda, long long strideA,
    const unsigned short* __restrict__ Bm, int ldb, long long strideB,
    const float* __restrict__ biasBase, int biasStride, int perZ,
    Outs5 outs, const float* __restrict__ resid, int K)
{
  constexpr int BK = 32;
  constexpr int WM = BM / WGM, WN = BN / WGN;
  constexpr int WR = WM / 16, WC = WN / 16;
  constexpr int CHA = BM * BK / 8;   // 16B chunks in A tile
  constexpr int CHB = BN * BK / 8;
  __shared__ unsigned short lds_a[2][BM * BK];
  __shared__ unsigned short lds_b[2][BN * BK];
  const int z = blockIdx.z;
  const int tid = threadIdx.x;
  const int wave = tid >> 6, lane = tid & 63;
  const int l16 = lane & 15, lhi = lane >> 4;
  const int wm = (wave / WGN) * WM, wn = (wave % WGN) * WN;
  const int m0 = blockIdx.x * BM, n0 = blockIdx.y * BN;
  const unsigned short* Ap = A + (long long)z * strideA;
  const unsigned short* Bp = Bm + (long long)z * strideB;

  auto stage = [&](int buf, int k0) {
#pragma unroll
    for (int p = 0; p < CHA / 256; ++p) {
      int t = p * 256 + tid;
      gload16(Ap + (long long)(m0 + (t >> 2)) * lda + k0 + (t & 3) * 8,
              &lds_a[buf][t * 8]);
    }
    if constexpr (CHA % 256) {
      if (tid < CHA % 256) {
        int t = (CHA / 256) * 256 + tid;
        gload16(Ap + (long long)(m0 + (t >> 2)) * lda + k0 + (t & 3) * 8,
                &lds_a[buf][t * 8]);
      }
    }
#pragma unroll
    for (int p = 0; p < CHB / 256; ++p) {
      int t = p * 256 + tid;
      gload16(Bp + (long long)(n0 + (t >> 2)) * ldb + k0 + (t & 3) * 8,
              &lds_b[buf][t * 8]);
    }
    if constexpr (CHB % 256) {
      if (tid < CHB % 256) {
        int t = (CHB / 256) * 256 + tid;
        gload16(Bp + (long long)(n0 + (t >> 2)) * ldb + k0 + (t & 3) * 8,
                &lds_b[buf][t * 8]);
      }
    }
  };

  f32x4 acc[WR][WC];
#pragma unroll
  for (int r = 0; r < WR; ++r)
#pragma unroll
    for (int c = 0; c < WC; ++c) { f32x4 zz = {0.f, 0.f, 0.f, 0.f}; acc[r][c] = zz; }

  stage(0, 0);
  __syncthreads();                      // compiler emits vmcnt(0) drain before barrier
  int cur = 0;
  for (int k0 = 0; k0 < K; k0 += BK) {
    if (k0 + BK < K) stage(cur ^ 1, k0 + BK);   // prefetch next tile (in flight over MFMA)
    s16x8 af[WR], bfv[WC];
#pragma unroll
    for (int r = 0; r < WR; ++r)
      af[r] = *(const s16x8*)&lds_a[cur][(wm + r * 16 + l16) * BK + lhi * 8];
#pragma unroll
    for (int c = 0; c < WC; ++c)
      bfv[c] = *(const s16x8*)&lds_b[cur][(wn + c * 16 + l16) * BK + lhi * 8];
#pragma unroll
    for (int r = 0; r < WR; ++r)
#pragma unroll
      for (int c = 0; c < WC; ++c)
        acc[r][c] = __builtin_amdgcn_mfma_f32_16x16x32_bf16(af[r], bfv[c], acc[r][c], 0, 0, 0);
    __syncthreads();                    // drains prefetch vmcnt + protects LDS reuse
    cur ^= 1;
  }

  OutSpec spec = perZ ? outs.o[z] : outs.o[0];
  const float* bias = biasBase ? (biasBase + (long long)z * biasStride) : nullptr;
#pragma unroll
  for (int r = 0; r < WR; ++r) {
#pragma unroll
    for (int c = 0; c < WC; ++c) {
      int n = n0 + wn + c * 16 + l16;
      int rb = m0 + wm + r * 16 + lhi * 4;
      float bv = bias ? bias[n] : 0.f;
      float vv[4];
#pragma unroll
      for (int j = 0; j < 4; ++j) vv[j] = acc[r][c][j] + bv;
      if (spec.mode == MODE_F32) {
#pragma unroll
        for (int j = 0; j < 4; ++j)
          ((float*)spec.ptr)[(long long)(rb + j) * 512 + n] = vv[j];
      } else if (spec.mode == MODE_VT) {             // V^T: (B,H,HD,S) bf16, packed 4-s store
        int b = rb >> 9, s = rb & 511;
        ushort4 pk;
        pk.x = f2b(vv[0]); pk.y = f2b(vv[1]); pk.z = f2b(vv[2]); pk.w = f2b(vv[3]);
        *(ushort4*)&((unsigned short*)spec.ptr)[
            (((long long)(b * 8 + (n >> 6))) * 64 + (n & 63)) * 512 + s] = pk;
      } else if (spec.mode == MODE_Y) {              // y = c + bias + resid
#pragma unroll
        for (int j = 0; j < 4; ++j)
          ((float*)spec.ptr)[(long long)(rb + j) * 512 + n] =
              vv[j] + resid[(long long)(rb + j) * 512 + n];
      } else if (spec.mode == MODE_SC) {             // bf16 scores, batched by z
#pragma unroll
        for (int j = 0; j < 4; ++j)
          ((unsigned short*)spec.ptr)[(long long)z * 262144 + (rb + j) * 512 + n] = f2b(vv[j]);
      } else {                                       // MODE_CTX: (B,S,D) bf16 from (b,h)
        int b = z >> 3, h = z & 7;
#pragma unroll
        for (int j = 0; j < 4; ++j)
          ((unsigned short*)spec.ptr)[((long long)(b * 512 + rb + j)) * 512 + h * 64 + n] = f2b(vv[j]);
      }
    }
  }
}

// ---------- weight transpose: Wt[l][mat][n][k] = bf16(W[l][k][n]) ----------
__global__ __launch_bounds__(256) void wt_k(Ptr6 srcs, unsigned short* __restrict__ wt) {
  __shared__ float tile[32][33];
  int zz = blockIdx.z;                    // zz = l*6 + mat
  int l = zz / 6, mat = zz % 6;
  const float* src = srcs.p[mat] + (long long)l * 262144;
  int tx = threadIdx.x, ty = threadIdx.y; // (32,8)
  int n0 = blockIdx.x * 32, k0 = blockIdx.y * 32;
#pragma unroll
  for (int r = 0; r < 4; ++r)
    tile[ty + r * 8][tx] = src[(long long)(k0 + ty + r * 8) * 512 + n0 + tx];
  __syncthreads();
#pragma unroll
  for (int r = 0; r < 4; ++r)
    wt[(long long)zz * 262144 + (long long)(n0 + ty + r * 8) * 512 + k0 + tx] =
        f2b(tile[tx][ty + r * 8]);
}

// ---------- bias packing + fused quantum matrices Ar=qwr@em, Ai=qwi@em ----------
__global__ __launch_bounds__(256) void prep_k(Ptr6 biases,
    const float* __restrict__ qwr, const float* __restrict__ qwi, const float* __restrict__ qem,
    const float* __restrict__ kwr, const float* __restrict__ kwi, const float* __restrict__ kem,
    float* __restrict__ biasPacked, float* __restrict__ ArAi) {
  int l = blockIdx.x, t = threadIdx.x;
  for (int m = 0; m < 6; ++m)
    for (int d = t; d < 512; d += 256)
      biasPacked[(l * 6 + m) * 512 + d] = biases.p[m][l * 512 + d];
  int i = t >> 4, j = t & 15;
  const float* em0 = qem + l * 256;
  float ar = 0.f, ai = 0.f;
  for (int tt = 0; tt < 16; ++tt) {
    ar += qwr[l * 256 + i * 16 + tt] * em0[tt * 16 + j];
    ai += qwi[l * 256 + i * 16 + tt] * em0[tt * 16 + j];
  }
  ArAi[(l * 4 + 0) * 256 + t] = ar;
  ArAi[(l * 4 + 1) * 256 + t] = ai;
  const float* em1 = kem + l * 256;
  ar = 0.f; ai = 0.f;
  for (int tt = 0; tt < 16; ++tt) {
    ar += kwr[l * 256 + i * 16 + tt] * em1[tt * 16 + j];
    ai += kwi[l * 256 + i * 16 + tt] * em1[tt * 16 + j];
  }
  ArAi[(l * 4 + 2) * 256 + t] = ar;
  ArAi[(l * 4 + 3) * 256 + t] = ai;
}

// ---------- visual projection partials + final proj sum ----------
__global__ __launch_bounds__(512) void vispart_k(const float* __restrict__ vis,
    const float* __restrict__ Wvis, float* __restrict__ part) {
  int b = blockIdx.x, chunk = blockIdx.y, d = threadIdx.x;
  float acc = 0.f;
  for (int k = chunk * 64; k < chunk * 64 + 64; ++k)
    acc += vis[b * 2048 + k] * Wvis[(long long)k * 512 + d];
  part[(b * 32 + chunk) * 512 + d] = acc;
}
__global__ __launch_bounds__(512) void projsum_k(const float* __restrict__ part,
    const float* __restrict__ bvis, const float* __restrict__ temporal,
    const float* __restrict__ Wtemp, const float* __restrict__ btemp, float* __restrict__ proj) {
  int b = blockIdx.x, d = threadIdx.x;
  float acc = bvis[d] + btemp[d];
  for (int c = 0; c < 32; ++c) acc += part[(b * 32 + c) * 512 + d];
  for (int k = 0; k < 64; ++k) acc += temporal[b * 64 + k] * Wtemp[k * 512 + d];
  proj[b * 512 + d] = acc;
}

// ---------- embedding + positional encoding ----------
__global__ __launch_bounds__(512) void embed_k(const int* __restrict__ text,
    const float* __restrict__ emb, const float* __restrict__ proj,
    float* __restrict__ x, unsigned short* __restrict__ xb) {
  int row = blockIdx.x;
  int b = row >> 9, s = row & 511;
  int d = threadIdx.x;
  int tok = text[row];
  float v = emb[(long long)tok * 512 + d] + proj[b * 512 + d];
  float fr = __expf((float)((d >> 1) << 1) * (-9.2103403719761836f / 512.f));
  float ang = (float)s * fr;
  v += (d & 1) ? cosf(ang) : sinf(ang);
  x[(long long)row * 512 + d] = v;
  xb[(long long)row * 512 + d] = f2b(v);
}

// ---------- quantum branch: qs = x@sg; probs = (qs@Ar)^2 + (qs@Ai)^2; fw ----------
__global__ __launch_bounds__(64) void quantum_k(const float* __restrict__ x,
    const float* __restrict__ sg_q, const float* __restrict__ sg_k,
    const float* __restrict__ ArAiL, float* __restrict__ qp, float* __restrict__ kp,
    float* __restrict__ fwq, float* __restrict__ fwk) {
  int row = blockIdx.x, side = blockIdx.y, lane = threadIdx.x;
  const float* sg = side ? sg_k : sg_q;
  const float* Ar = ArAiL + side * 512;
  const float* Ai = Ar + 256;
  float acc[16];
#pragma unroll
  for (int j = 0; j < 16; ++j) acc[j] = 0.f;
  const float* xr = x + (long long)row * 512;
#pragma unroll
  for (int kk = 0; kk < 8; ++kk) {
    float xv = xr[kk * 64 + lane];
    const float* sgr = sg + (kk * 64 + lane) * 16;
#pragma unroll
    for (int j = 0; j < 16; ++j) acc[j] += xv * sgr[j];
  }
  // full-wave butterfly: every lane ends with all 16 qs sums
#pragma unroll
  for (int s = 32; s; s >>= 1)
#pragma unroll
    for (int j = 0; j < 16; ++j) acc[j] += __shfl_xor(acc[j], s);
  int j = lane & 15;
  float tr = 0.f, ti = 0.f;
#pragma unroll
  for (int t = 0; t < 16; ++t) {
    tr += acc[t] * Ar[t * 16 + j];
    ti += acc[t] * Ai[t * 16 + j];
  }
  float p = tr * tr + ti * ti;
  float ps = p;
#pragma unroll
  for (int s = 1; s < 16; s <<= 1) ps += __shfl_xor(ps, s);
  if (lane < 16) (side ? kp : qp)[row * 16 + lane] = p;
  if (lane == 0) (side ? fwk : fwq)[row] = 1.f / (1.f + __expf(-ps * (1.f / 16.f)));
}

// ---------- fuse (both sides in one launch, blockIdx.y = side) ----------
struct FuseP {
  const float* lin; const float* cl; const float* qp; const float* fw;
  const float* mb; unsigned short* ext; float sA, sB;
};
struct Fuse2 { FuseP s[2]; };
__global__ __launch_bounds__(512) void fuse_k(Fuse2 fp) {
  FuseP P = fp.s[blockIdx.y];
  int row = blockIdx.x;
  int b = row >> 9, i = row & 511;
  int d = threadIdx.x;
  const float* qpr = P.qp + row * 16;
  float fwv = P.fw[row];
  float qout = 0.f;
#pragma unroll
  for (int t = 0; t < 16; ++t) qout += qpr[t] * P.mb[t * 512 + d];
  float qq = fwv * qout + (1.f - fwv) * tanhf(P.cl[(long long)row * 512 + d]);
  float val = (0.7f * P.lin[(long long)row * 512 + d] + 0.3f * qq) * P.sA;
  int h = d >> 6, dd = d & 63;
  P.ext[(((long long)(b * 8 + h)) * 512 + i) * 96 + dd] = f2b(val);
  if (d < 128) {
    int h2 = d >> 4, j = d & 15;
    P.ext[(((long long)(b * 8 + h2)) * 512 + i) * 96 + 64 + j] = f2b(P.sB * qpr[j]);
  } else if (d < 256) {
    int t2 = d - 128;
    int h2 = t2 >> 4, j = t2 & 15;
    P.ext[(((long long)(b * 8 + h2)) * 512 + i) * 96 + 80 + j] = 0;
  }
}

// ---------- wave-per-row softmax: bf16 scores -> fp32 attn (d_out) + bf16 attn in-place ----------
__global__ __launch_bounds__(256) void softmax_k(unsigned short* __restrict__ sc,
                                                 float* __restrict__ attn) {
  int wv = threadIdx.x >> 6, lane = threadIdx.x & 63;
  long long row = (long long)blockIdx.x * 4 + wv;
  unsigned short* sp = sc + row * 512 + lane * 8;
  s16x8 v = *(const s16x8*)sp;
  float f[8], mx = -3.4e38f;
#pragma unroll
  for (int j = 0; j < 8; ++j) { f[j] = b2f((unsigned short)v[j]); mx = fmaxf(mx, f[j]); }
#pragma unroll
  for (int s = 32; s; s >>= 1) mx = fmaxf(mx, __shfl_xor(mx, s));
  float e[8], sum = 0.f;
#pragma unroll
  for (int j = 0; j < 8; ++j) { e[j] = __expf(f[j] - mx); sum += e[j]; }
#pragma unroll
  for (int s = 32; s; s >>= 1) sum += __shfl_xor(sum, s);
  float inv = 1.f / sum;
  float* ap = attn + row * 512 + lane * 8;
  f32x4 o0, o1; s16x8 ob;
#pragma unroll
  for (int j = 0; j < 4; ++j) { o0[j] = e[j] * inv; ob[j] = (short)f2b(o0[j]); }
#pragma unroll
  for (int j = 0; j < 4; ++j) { o1[j] = e[4 + j] * inv; ob[4 + j] = (short)f2b(o1[j]); }
  *(f32x4*)ap = o0;
  *(f32x4*)(ap + 4) = o1;
  *(s16x8*)sp = ob;                      // bf16 attn for the ctx GEMM
}

// ---------- wave-per-row layernorm ----------
__global__ __launch_bounds__(256) void ln_k(const float* __restrict__ y,
    const float* __restrict__ g, const float* __restrict__ be,
    float* __restrict__ xo, unsigned short* __restrict__ xb, float* __restrict__ xo2) {
  int wv = threadIdx.x >> 6, lane = threadIdx.x & 63;
  long long row = (long long)blockIdx.x * 4 + wv;
  const float* yr = y + row * 512 + lane * 8;
  f32x4 a = *(const f32x4*)yr, b = *(const f32x4*)(yr + 4);
  float s = a[0] + a[1] + a[2] + a[3] + b[0] + b[1] + b[2] + b[3];
#pragma unroll
  for (int m = 32; m; m >>= 1) s += __shfl_xor(s, m);
  float mu = s * (1.f / 512.f);
  float d[8], vs = 0.f;
#pragma unroll
  for (int j = 0; j < 4; ++j) { d[j] = a[j] - mu; vs += d[j] * d[j]; }
#pragma unroll
  for (int j = 0; j < 4; ++j) { d[4 + j] = b[j] - mu; vs += d[4 + j] * d[4 + j]; }
#pragma unroll
  for (int m = 32; m; m >>= 1) vs += __shfl_xor(vs, m);
  float rstd = rsqrtf(vs * (1.f / 512.f) + 1e-5f);
  f32x4 g0 = *(const f32x4*)(g + lane * 8), g1 = *(const f32x4*)(g + lane * 8 + 4);
  f32x4 b0 = *(const f32x4*)(be + lane * 8), b1 = *(const f32x4*)(be + lane * 8 + 4);
  f32x4 o0, o1; s16x8 ob;
#pragma unroll
  for (int j = 0; j < 4; ++j) { o0[j] = d[j] * rstd * g0[j] + b0[j]; ob[j] = (short)f2b(o0[j]); }
#pragma unroll
  for (int j = 0; j < 4; ++j) { o1[j] = d[4 + j] * rstd * g1[j] + b1[j]; ob[4 + j] = (short)f2b(o1[j]); }
  float* xr = xo + row * 512 + lane * 8;
  *(f32x4*)xr = o0; *(f32x4*)(xr + 4) = o1;
  *(s16x8*)(xb + row * 512 + lane * 8) = ob;
  if (xo2) {
    float* x2 = xo2 + row * 512 + lane * 8;
    *(f32x4*)x2 = o0; *(f32x4*)(x2 + 4) = o1;
  }
}

// ---------- pooled heads ----------
__global__ __launch_bounds__(512) void head_k(const float* __restrict__ x,
    const float* __restrict__ Ws, const float* __restrict__ bs,
    const float* __restrict__ Wd, const float* __restrict__ bd,
    const float* __restrict__ We, const float* __restrict__ be, float* __restrict__ out) {
  __shared__ float pooled[512];
  __shared__ float dl[5];
  int b = blockIdx.x, d = threadIdx.x;
  float s = 0.f;
  for (int t = 0; t < 512; ++t) s += x[((long long)(b * 512 + t)) * 512 + d];
  pooled[d] = s * (1.f / 512.f);
  __syncthreads();
  if (d < 64) {
    float a = bs[d];
    for (int t = 0; t < 512; ++t) a += pooled[t] * Ws[t * 64 + d];
    out[b * 64 + d] = 1.f / (1.f + __expf(-a));
  } else if (d < 69) {
    int j = d - 64;
    float a = bd[j];
    for (int t = 0; t < 512; ++t) a += pooled[t] * Wd[t * 5 + j];
    dl[j] = a;
  } else if (d == 69) {
    float a = be[0];
    for (int t = 0; t < 512; ++t) a += pooled[t] * We[t];
    out[276 + b] = 1.f / (1.f + __expf(-a));
  }
  __syncthreads();
  if (d < 5) {
    float mx = dl[0];
    for (int j = 1; j < 5; ++j) mx = fmaxf(mx, dl[j]);
    float sm = 0.f;
    for (int j = 0; j < 5; ++j) sm += __expf(dl[j] - mx);
    out[256 + b * 5 + d] = __expf(dl[d] - mx) / sm;
  }
}

// ---------- host ----------
extern "C" void kernel_launch(void* const* d_in, const int* in_sizes, int n_in,
                              void* d_out, int out_size, void* d_ws, size_t ws_size,
                              hipStream_t stream) {
  (void)in_sizes; (void)n_in; (void)out_size; (void)ws_size;
  const int*   text     = (const int*)  d_in[0];
  const float* visual   = (const float*)d_in[1];
  const float* temporal = (const float*)d_in[2];
  const float* embedw   = (const float*)d_in[3];
  const float* Wvis  = (const float*)d_in[4];  const float* bvis  = (const float*)d_in[5];
  const float* Wtemp = (const float*)d_in[6];  const float* btemp = (const float*)d_in[7];
  const float* Wq = (const float*)d_in[8];   const float* bq = (const float*)d_in[9];
  const float* Wk = (const float*)d_in[10];  const float* bk = (const float*)d_in[11];
  const float* Wv = (const float*)d_in[12];  const float* bv = (const float*)d_in[13];
  const float* Wo = (const float*)d_in[14];  const float* bo = (const float*)d_in[15];
  const float* qW = (const float*)d_in[16];  const float* qb = (const float*)d_in[17];
  const float* q_qwr = (const float*)d_in[18]; const float* q_qwi = (const float*)d_in[19];
  const float* q_sg  = (const float*)d_in[20]; const float* q_em  = (const float*)d_in[21];
  const float* q_mb  = (const float*)d_in[22];
  const float* kW = (const float*)d_in[23];  const float* kb = (const float*)d_in[24];
  const float* k_qwr = (const float*)d_in[25]; const float* k_qwi = (const float*)d_in[26];
  const float* k_sg  = (const float*)d_in[27]; const float* k_em  = (const float*)d_in[28];
  const float* k_mb  = (const float*)d_in[29];
  const float* ln_g = (const float*)d_in[30]; const float* ln_b = (const float*)d_in[31];
  const float* Ws = (const float*)d_in[32];  const float* bs_ = (const float*)d_in[33];
  const float* Wd = (const float*)d_in[34];  const float* bd = (const float*)d_in[35];
  const float* We = (const float*)d_in[36];  const float* be = (const float*)d_in[37];
  float* out = (float*)d_out;

  char* w = (char*)d_ws;
  auto alloc = [&](size_t bytes) {
    char* p = w;
    w += (bytes + 255) & ~(size_t)255;
    return p;
  };
  float* ws_x   = (float*)alloc(2048ll * 512 * 4);
  unsigned short* ws_xb = (unsigned short*)alloc(2048ll * 512 * 2);
  unsigned short* ws_Wt = (unsigned short*)alloc(36ll * 262144 * 2);
  float* ws_bias = (float*)alloc(6ll * 6 * 512 * 4);
  float* ws_ArAi = (float*)alloc(6ll * 1024 * 4);
  float* ws_proj = (float*)alloc(4ll * 512 * 4);
  float* ws_vp   = (float*)alloc(4ll * 32 * 512 * 4);
  float* ws_Q    = (float*)alloc(2048ll * 512 * 4);
  float* ws_K    = (float*)alloc(2048ll * 512 * 4);
  float* ws_Cq   = (float*)alloc(2048ll * 512 * 4);
  float* ws_Ck   = (float*)alloc(2048ll * 512 * 4);
  float* ws_qp   = (float*)alloc(2048ll * 16 * 4);
  float* ws_kp   = (float*)alloc(2048ll * 16 * 4);
  float* ws_fwq  = (float*)alloc(2048ll * 4);
  float* ws_fwk  = (float*)alloc(2048ll * 4);
  unsigned short* ws_Vt   = (unsigned short*)alloc(2048ll * 512 * 2);
  unsigned short* ws_Qext = (unsigned short*)alloc(4ll * 8 * 512 * 96 * 2);
  unsigned short* ws_Kext = (unsigned short*)alloc(4ll * 8 * 512 * 96 * 2);
  unsigned short* ws_sc   = (unsigned short*)alloc(4ll * 8 * 512 * 512 * 2);
  unsigned short* ws_ctx  = (unsigned short*)alloc(2048ll * 512 * 2);
  float* ws_y    = (float*)alloc(2048ll * 512 * 4);

  // preprocess (per call — deterministic)
  Ptr6 wsrc = {{Wq, Wk, Wv, qW, kW, Wo}};
  wt_k<<<dim3(16, 16, 36), dim3(32, 8), 0, stream>>>(wsrc, ws_Wt);
  Ptr6 bsrc = {{bq, bk, bv, qb, kb, bo}};
  prep_k<<<dim3(6), dim3(256), 0, stream>>>(bsrc, q_qwr, q_qwi, q_em, k_qwr, k_qwi, k_em,
                                            ws_bias, ws_ArAi);
  vispart_k<<<dim3(4, 32), dim3(512), 0, stream>>>(visual, Wvis, ws_vp);
  projsum_k<<<dim3(4), dim3(512), 0, stream>>>(ws_vp, bvis, temporal, Wtemp, btemp, ws_proj);
  embed_k<<<dim3(2048), dim3(512), 0, stream>>>(text, embedw, ws_proj, ws_x, ws_xb);

  const long long ATTN_OFF = 280ll + 1048576ll;  // skill(256)+diff(20)+eng(4)+x(1048576)
  for (int l = 0; l < 6; ++l) {
    const unsigned short* WtL = ws_Wt + (long long)l * 6 * 262144;
    const float* biasL = ws_bias + (long long)l * 6 * 512;

    // 5-way batched GEMM: Q, K, V(->Vt bf16), Cq, Ck
    Outs5 o5{};
    o5.o[0] = { ws_Q, MODE_F32 };  o5.o[1] = { ws_K, MODE_F32 };
    o5.o[2] = { ws_Vt, MODE_VT };  o5.o[3] = { ws_Cq, MODE_F32 };
    o5.o[4] = { ws_Ck, MODE_F32 };
    gemm_nt<128, 128, 2, 2><<<dim3(16, 4, 5), 256, 0, stream>>>(
        ws_xb, 512, 0ll, WtL, 512, 262144ll, biasL, 512, 1, o5, nullptr, 512);

    quantum_k<<<dim3(2048, 2), 64, 0, stream>>>(ws_x, q_sg + l * 8192, k_sg + l * 8192,
        ws_ArAi + l * 1024, ws_qp, ws_kp, ws_fwq, ws_fwk);

    // fuse both sides; Qext gets 1/8 scale and the 0.1 interference scale folded in
    Fuse2 f2{};
    f2.s[0] = { ws_Q, ws_Cq, ws_qp, ws_fwq, q_mb + l * 8192, ws_Qext, 0.125f, 0.1f };
    f2.s[1] = { ws_K, ws_Ck, ws_kp, ws_fwk, k_mb + l * 8192, ws_Kext, 1.0f, 1.0f };
    fuse_k<<<dim3(2048, 2), dim3(512), 0, stream>>>(f2);

    // scores (K=96 includes interference block), bf16 out
    Outs5 osc{};
    osc.o[0] = { ws_sc, MODE_SC };
    gemm_nt<128, 128, 2, 2><<<dim3(4, 4, 32), 256, 0, stream>>>(
        ws_Qext, 96, 512ll * 96, ws_Kext, 96, 512ll * 96, nullptr, 0, 0, osc, nullptr, 96);

    float* attnL = out + ATTN_OFF + (long long)l * 8388608;
    softmax_k<<<dim3(4096), dim3(256), 0, stream>>>(ws_sc, attnL);

    // ctx = attn(bf16, in-place over sc) @ V
    Outs5 octx{};
    octx.o[0] = { ws_ctx, MODE_CTX };
    gemm_nt<64, 64, 2, 2><<<dim3(8, 1, 32), 256, 0, stream>>>(
        ws_sc, 512, 262144ll, ws_Vt, 512, 32768ll, nullptr, 0, 0, octx, nullptr, 512);

    // y = ctx @ Wo + bo + x
    Outs5 oy{};
    oy.o[0] = { ws_y, MODE_Y };
    gemm_nt<64, 64, 2, 2><<<dim3(32, 8, 1), 256, 0, stream>>>(
        ws_ctx, 512, 0ll, WtL + 5 * 262144, 512, 0ll, biasL + 5 * 512, 0, 0, oy, ws_x, 512);

    ln_k<<<dim3(512), dim3(256), 0, stream>>>(ws_y, ln_g + l * 512, ln_b + l * 512,
        ws_x, ws_xb, (l == 5) ? (out + 280) : nullptr);
  }

  head_k<<<dim3(4), dim3(512), 0, stream>>>(ws_x, Ws, bs_, Wd, bd, We, be, out);
}

// Round 3
// 507.840 us; speedup vs baseline: 1.6182x; 1.2234x over previous
//
#include <hip/hip_runtime.h>
#include <hip/hip_bf16.h>

// ---------- types / helpers ----------
typedef __attribute__((ext_vector_type(4))) float f32x4;
typedef __attribute__((ext_vector_type(8))) short s16x8;

__device__ __forceinline__ unsigned short f2b(float f) {
  unsigned int u = __float_as_uint(f);
  unsigned int r = (u + 0x7FFFu + ((u >> 16) & 1u)) >> 16;   // RNE f32->bf16
  return (unsigned short)r;
}
__device__ __forceinline__ float b2f(unsigned short h) {
  return __uint_as_float(((unsigned int)h) << 16);
}
__device__ __forceinline__ void gload16(const void* g, void* l) {
  __builtin_amdgcn_global_load_lds(
      (const __attribute__((address_space(1))) void*)g,
      (__attribute__((address_space(3))) void*)l, 16, 0, 0);
}

enum { MODE_F32 = 0, MODE_VT = 1, MODE_Y = 2 };
struct OutSpec { void* ptr; int mode; };
struct Outs5 { OutSpec o[5]; };
struct Ptr6 { const float* p[6]; };

// ---------- generic NT MFMA GEMM: C[m][n] = sum_k A[m][k]*B[n][k] (+bias)(+resid) ----------
template<int BM, int BN, int WGM, int WGN>
__global__ __launch_bounds__(256) void gemm_nt(
    const unsigned short* __restrict__ A, int lda, long long strideA,
    const unsigned short* __restrict__ Bm, int ldb, long long strideB,
    const float* __restrict__ biasBase, int biasStride, int perZ,
    Outs5 outs, const float* __restrict__ resid, int K)
{
  constexpr int BK = 32;
  constexpr int WM = BM / WGM, WN = BN / WGN;
  constexpr int WR = WM / 16, WC = WN / 16;
  constexpr int CHA = BM * BK / 8;
  constexpr int CHB = BN * BK / 8;
  __shared__ unsigned short lds_a[2][BM * BK];
  __shared__ unsigned short lds_b[2][BN * BK];
  const int z = blockIdx.z;
  const int tid = threadIdx.x;
  const int wave = tid >> 6, lane = tid & 63;
  const int l16 = lane & 15, lhi = lane >> 4;
  const int wm = (wave / WGN) * WM, wn = (wave % WGN) * WN;
  const int m0 = blockIdx.x * BM, n0 = blockIdx.y * BN;
  const unsigned short* Ap = A + (long long)z * strideA;
  const unsigned short* Bp = Bm + (long long)z * strideB;

  auto stage = [&](int buf, int k0) {
#pragma unroll
    for (int p = 0; p < CHA / 256; ++p) {
      int t = p * 256 + tid;
      gload16(Ap + (long long)(m0 + (t >> 2)) * lda + k0 + (t & 3) * 8, &lds_a[buf][t * 8]);
    }
    if constexpr (CHA % 256) {
      if (tid < CHA % 256) {
        int t = (CHA / 256) * 256 + tid;
        gload16(Ap + (long long)(m0 + (t >> 2)) * lda + k0 + (t & 3) * 8, &lds_a[buf][t * 8]);
      }
    }
#pragma unroll
    for (int p = 0; p < CHB / 256; ++p) {
      int t = p * 256 + tid;
      gload16(Bp + (long long)(n0 + (t >> 2)) * ldb + k0 + (t & 3) * 8, &lds_b[buf][t * 8]);
    }
    if constexpr (CHB % 256) {
      if (tid < CHB % 256) {
        int t = (CHB / 256) * 256 + tid;
        gload16(Bp + (long long)(n0 + (t >> 2)) * ldb + k0 + (t & 3) * 8, &lds_b[buf][t * 8]);
      }
    }
  };

  f32x4 acc[WR][WC];
#pragma unroll
  for (int r = 0; r < WR; ++r)
#pragma unroll
    for (int c = 0; c < WC; ++c) { f32x4 zz = {0.f, 0.f, 0.f, 0.f}; acc[r][c] = zz; }

  stage(0, 0);
  __syncthreads();
  int cur = 0;
  for (int k0 = 0; k0 < K; k0 += BK) {
    if (k0 + BK < K) stage(cur ^ 1, k0 + BK);
    s16x8 af[WR], bfv[WC];
#pragma unroll
    for (int r = 0; r < WR; ++r)
      af[r] = *(const s16x8*)&lds_a[cur][(wm + r * 16 + l16) * BK + lhi * 8];
#pragma unroll
    for (int c = 0; c < WC; ++c)
      bfv[c] = *(const s16x8*)&lds_b[cur][(wn + c * 16 + l16) * BK + lhi * 8];
#pragma unroll
    for (int r = 0; r < WR; ++r)
#pragma unroll
      for (int c = 0; c < WC; ++c)
        acc[r][c] = __builtin_amdgcn_mfma_f32_16x16x32_bf16(af[r], bfv[c], acc[r][c], 0, 0, 0);
    __syncthreads();
    cur ^= 1;
  }

  OutSpec spec = perZ ? outs.o[z] : outs.o[0];
  const float* bias = biasBase ? (biasBase + (long long)z * biasStride) : nullptr;
#pragma unroll
  for (int r = 0; r < WR; ++r) {
#pragma unroll
    for (int c = 0; c < WC; ++c) {
      int n = n0 + wn + c * 16 + l16;
      int rb = m0 + wm + r * 16 + lhi * 4;
      float bv = bias ? bias[n] : 0.f;
      float vv[4];
#pragma unroll
      for (int j = 0; j < 4; ++j) vv[j] = acc[r][c][j] + bv;
      if (spec.mode == MODE_F32) {
#pragma unroll
        for (int j = 0; j < 4; ++j)
          ((float*)spec.ptr)[(long long)(rb + j) * 512 + n] = vv[j];
      } else if (spec.mode == MODE_VT) {             // V^T: (B,H,HD,S) bf16
        int b = rb >> 9, s = rb & 511;
        ushort4 pk;
        pk.x = f2b(vv[0]); pk.y = f2b(vv[1]); pk.z = f2b(vv[2]); pk.w = f2b(vv[3]);
        *(ushort4*)&((unsigned short*)spec.ptr)[
            (((long long)(b * 8 + (n >> 6))) * 64 + (n & 63)) * 512 + s] = pk;
      } else {                                       // MODE_Y: y = c + bias + resid
#pragma unroll
        for (int j = 0; j < 4; ++j)
          ((float*)spec.ptr)[(long long)(rb + j) * 512 + n] =
              vv[j] + resid[(long long)(rb + j) * 512 + n];
      }
    }
  }
}

// ---------- fused attention: scores -> softmax -> attn(fp32 out) -> PV -> ctx ----------
// grid (32 z, 8 rb), 256 thr. Qe/Ke: (z,s,96) bf16; Vt: (z,hd,s) bf16.
// LDS phase1: Q[64][96] @0, K[512][96] @6144 (shorts). Phase2: S[64][512] @0, V[64][256] @32768.
__global__ __launch_bounds__(256, 1) void fused_attn(
    const unsigned short* __restrict__ Qe, const unsigned short* __restrict__ Ke,
    const unsigned short* __restrict__ Vt, float* __restrict__ attn,
    unsigned short* __restrict__ ctx)
{
  __shared__ unsigned short lds[55296];   // 110.6 KB
  const int z = blockIdx.x, rb = blockIdx.y;
  const int m0 = rb * 64;
  const int b = z >> 3, h = z & 7;
  const int tid = threadIdx.x;
  const int w = tid >> 6, lane = tid & 63;
  const int l16 = lane & 15, lhi = lane >> 4;
  const int rx3 = l16 & 3, rx7 = l16 & 7;

  // ---- stage Q (768 chunks) + K (6144 chunks), pre-swizzled source ----
#pragma unroll
  for (int p = 0; p < 3; ++p) {
    int t = p * 256 + tid;
    int row = t / 12, c = t % 12;
    gload16(Qe + ((long long)(z * 512 + m0 + row)) * 96 + (c ^ (row & 3)) * 8, &lds[t * 8]);
  }
#pragma unroll
  for (int p = 0; p < 24; ++p) {
    int t = p * 256 + tid;
    int row = t / 12, c = t % 12;
    gload16(Ke + ((long long)(z * 512 + row)) * 96 + (c ^ (row & 3)) * 8, &lds[6144 + t * 8]);
  }
  __syncthreads();

  // ---- scores: wave w owns rows m0+16w..+15, all 512 kv cols ----
  const unsigned short* Qs = lds;
  const unsigned short* Ks = lds + 6144;
  s16x8 aq[3];
#pragma unroll
  for (int kk = 0; kk < 3; ++kk)
    aq[kk] = *(const s16x8*)&Qs[(w * 16 + l16) * 96 + (kk * 4 + (lhi ^ rx3)) * 8];
  f32x4 acc[32];
#pragma unroll
  for (int c = 0; c < 32; ++c) { f32x4 zz = {0.f, 0.f, 0.f, 0.f}; acc[c] = zz; }
#pragma unroll
  for (int c = 0; c < 32; ++c) {
#pragma unroll
    for (int kk = 0; kk < 3; ++kk) {
      s16x8 bf = *(const s16x8*)&Ks[(c * 16 + l16) * 96 + (kk * 4 + (lhi ^ rx3)) * 8];
      acc[c] = __builtin_amdgcn_mfma_f32_16x16x32_bf16(aq[kk], bf, acc[c], 0, 0, 0);
    }
  }

  // ---- softmax stats in-register (rows = lhi*4+j, cols spread over l16 + frag) ----
  float inv[4];
#pragma unroll
  for (int j = 0; j < 4; ++j) {
    float mx = acc[0][j];
#pragma unroll
    for (int c = 1; c < 32; ++c) mx = fmaxf(mx, acc[c][j]);
    mx = fmaxf(mx, __shfl_xor(mx, 1));
    mx = fmaxf(mx, __shfl_xor(mx, 2));
    mx = fmaxf(mx, __shfl_xor(mx, 4));
    mx = fmaxf(mx, __shfl_xor(mx, 8));
    float sum = 0.f;
#pragma unroll
    for (int c = 0; c < 32; ++c) { float e = __expf(acc[c][j] - mx); acc[c][j] = e; sum += e; }
    sum += __shfl_xor(sum, 1);
    sum += __shfl_xor(sum, 2);
    sum += __shfl_xor(sum, 4);
    sum += __shfl_xor(sum, 8);
    inv[j] = 1.f / sum;
  }
  __syncthreads();                       // all waves done reading Q/K LDS

  // ---- stage V half 0 (64 rows x 256 kv), overlaps with S/attn writes ----
#pragma unroll
  for (int p = 0; p < 8; ++p) {
    int t = p * 256 + tid;
    int row = t >> 5, c = t & 31;
    gload16(Vt + (long long)z * 32768 + row * 512 + (c ^ (row & 7)) * 8, &lds[32768 + t * 8]);
  }
  // ---- write attn fp32 (d_out) + normalized bf16 P into S LDS ----
  unsigned short* S = lds;
  {
    float* ap = attn + (long long)z * 262144;
#pragma unroll
    for (int j = 0; j < 4; ++j) {
      int row_l = w * 16 + lhi * 4 + j;
      int rs = row_l & 7;
      float* arow = ap + (long long)(m0 + row_l) * 512;
      unsigned short* srow = S + row_l * 512;
#pragma unroll
      for (int c = 0; c < 32; ++c) {
        float p = acc[c][j] * inv[j];
        int col = c * 16 + l16;
        arow[col] = p;
        srow[((col >> 3) ^ rs) * 8 + (col & 7)] = f2b(p);
      }
    }
  }
  __syncthreads();                       // V half0 staged + S visible

  // ---- PV: ctx[16 rows][64 hd] per wave, K=512 in two halves ----
  const unsigned short* Vl = lds + 32768;
  f32x4 acc2[4];
#pragma unroll
  for (int c2 = 0; c2 < 4; ++c2) { f32x4 zz = {0.f, 0.f, 0.f, 0.f}; acc2[c2] = zz; }
  const int qrow = w * 16 + l16;
#pragma unroll
  for (int kk = 0; kk < 8; ++kk) {
    s16x8 a = *(const s16x8*)&S[qrow * 512 + ((kk * 4 + lhi) ^ rx7) * 8];
#pragma unroll
    for (int c2 = 0; c2 < 4; ++c2) {
      s16x8 bf = *(const s16x8*)&Vl[(c2 * 16 + l16) * 256 + ((kk * 4 + lhi) ^ rx7) * 8];
      acc2[c2] = __builtin_amdgcn_mfma_f32_16x16x32_bf16(a, bf, acc2[c2], 0, 0, 0);
    }
  }
  __syncthreads();                       // done reading V half0
#pragma unroll
  for (int p = 0; p < 8; ++p) {          // stage V half 1
    int t = p * 256 + tid;
    int row = t >> 5, c = t & 31;
    gload16(Vt + (long long)z * 32768 + row * 512 + 256 + (c ^ (row & 7)) * 8,
            &lds[32768 + t * 8]);
  }
  __syncthreads();
#pragma unroll
  for (int kk = 8; kk < 16; ++kk) {
    s16x8 a = *(const s16x8*)&S[qrow * 512 + ((kk * 4 + lhi) ^ rx7) * 8];
#pragma unroll
    for (int c2 = 0; c2 < 4; ++c2) {
      s16x8 bf = *(const s16x8*)&Vl[(c2 * 16 + l16) * 256 + (((kk - 8) * 4 + lhi) ^ rx7) * 8];
      acc2[c2] = __builtin_amdgcn_mfma_f32_16x16x32_bf16(a, bf, acc2[c2], 0, 0, 0);
    }
  }
  // ---- ctx store: (B,S,D) bf16 ----
#pragma unroll
  for (int c2 = 0; c2 < 4; ++c2) {
#pragma unroll
    for (int j = 0; j < 4; ++j) {
      int row_g = m0 + w * 16 + lhi * 4 + j;
      ctx[((long long)(b * 512 + row_g)) * 512 + h * 64 + c2 * 16 + l16] = f2b(acc2[c2][j]);
    }
  }
}

// ---------- weight transpose ----------
__global__ __launch_bounds__(256) void wt_k(Ptr6 srcs, unsigned short* __restrict__ wt) {
  __shared__ float tile[32][33];
  int zz = blockIdx.z;
  int l = zz / 6, mat = zz % 6;
  const float* src = srcs.p[mat] + (long long)l * 262144;
  int tx = threadIdx.x, ty = threadIdx.y;
  int n0 = blockIdx.x * 32, k0 = blockIdx.y * 32;
#pragma unroll
  for (int r = 0; r < 4; ++r)
    tile[ty + r * 8][tx] = src[(long long)(k0 + ty + r * 8) * 512 + n0 + tx];
  __syncthreads();
#pragma unroll
  for (int r = 0; r < 4; ++r)
    wt[(long long)zz * 262144 + (long long)(n0 + ty + r * 8) * 512 + k0 + tx] =
        f2b(tile[tx][ty + r * 8]);
}

// ---------- bias packing + fused quantum matrices ----------
__global__ __launch_bounds__(256) void prep_k(Ptr6 biases,
    const float* __restrict__ qwr, const float* __restrict__ qwi, const float* __restrict__ qem,
    const float* __restrict__ kwr, const float* __restrict__ kwi, const float* __restrict__ kem,
    float* __restrict__ biasPacked, float* __restrict__ ArAi) {
  int l = blockIdx.x, t = threadIdx.x;
  for (int m = 0; m < 6; ++m)
    for (int d = t; d < 512; d += 256)
      biasPacked[(l * 6 + m) * 512 + d] = biases.p[m][l * 512 + d];
  int i = t >> 4, j = t & 15;
  const float* em0 = qem + l * 256;
  float ar = 0.f, ai = 0.f;
  for (int tt = 0; tt < 16; ++tt) {
    ar += qwr[l * 256 + i * 16 + tt] * em0[tt * 16 + j];
    ai += qwi[l * 256 + i * 16 + tt] * em0[tt * 16 + j];
  }
  ArAi[(l * 4 + 0) * 256 + t] = ar;
  ArAi[(l * 4 + 1) * 256 + t] = ai;
  const float* em1 = kem + l * 256;
  ar = 0.f; ai = 0.f;
  for (int tt = 0; tt < 16; ++tt) {
    ar += kwr[l * 256 + i * 16 + tt] * em1[tt * 16 + j];
    ai += kwi[l * 256 + i * 16 + tt] * em1[tt * 16 + j];
  }
  ArAi[(l * 4 + 2) * 256 + t] = ar;
  ArAi[(l * 4 + 3) * 256 + t] = ai;
}

// ---------- visual projection ----------
__global__ __launch_bounds__(512) void vispart_k(const float* __restrict__ vis,
    const float* __restrict__ Wvis, float* __restrict__ part) {
  int b = blockIdx.x, chunk = blockIdx.y, d = threadIdx.x;
  float acc = 0.f;
  for (int k = chunk * 64; k < chunk * 64 + 64; ++k)
    acc += vis[b * 2048 + k] * Wvis[(long long)k * 512 + d];
  part[(b * 32 + chunk) * 512 + d] = acc;
}
__global__ __launch_bounds__(512) void projsum_k(const float* __restrict__ part,
    const float* __restrict__ bvis, const float* __restrict__ temporal,
    const float* __restrict__ Wtemp, const float* __restrict__ btemp, float* __restrict__ proj) {
  int b = blockIdx.x, d = threadIdx.x;
  float acc = bvis[d] + btemp[d];
  for (int c = 0; c < 32; ++c) acc += part[(b * 32 + c) * 512 + d];
  for (int k = 0; k < 64; ++k) acc += temporal[b * 64 + k] * Wtemp[k * 512 + d];
  proj[b * 512 + d] = acc;
}

// ---------- embedding + positional encoding ----------
__global__ __launch_bounds__(512) void embed_k(const int* __restrict__ text,
    const float* __restrict__ emb, const float* __restrict__ proj,
    float* __restrict__ x, unsigned short* __restrict__ xb) {
  int row = blockIdx.x;
  int b = row >> 9, s = row & 511;
  int d = threadIdx.x;
  int tok = text[row];
  float v = emb[(long long)tok * 512 + d] + proj[b * 512 + d];
  float fr = __expf((float)((d >> 1) << 1) * (-9.2103403719761836f / 512.f));
  float ang = (float)s * fr;
  v += (d & 1) ? cosf(ang) : sinf(ang);
  x[(long long)row * 512 + d] = v;
  xb[(long long)row * 512 + d] = f2b(v);
}

// ---------- quantum branch ----------
__global__ __launch_bounds__(64) void quantum_k(const float* __restrict__ x,
    const float* __restrict__ sg_q, const float* __restrict__ sg_k,
    const float* __restrict__ ArAiL, float* __restrict__ qp, float* __restrict__ kp,
    float* __restrict__ fwq, float* __restrict__ fwk) {
  int row = blockIdx.x, side = blockIdx.y, lane = threadIdx.x;
  const float* sg = side ? sg_k : sg_q;
  const float* Ar = ArAiL + side * 512;
  const float* Ai = Ar + 256;
  float acc[16];
#pragma unroll
  for (int j = 0; j < 16; ++j) acc[j] = 0.f;
  const float* xr = x + (long long)row * 512;
#pragma unroll
  for (int kk = 0; kk < 8; ++kk) {
    float xv = xr[kk * 64 + lane];
    const float* sgr = sg + (kk * 64 + lane) * 16;
#pragma unroll
    for (int j = 0; j < 16; ++j) acc[j] += xv * sgr[j];
  }
#pragma unroll
  for (int s = 32; s; s >>= 1)
#pragma unroll
    for (int j = 0; j < 16; ++j) acc[j] += __shfl_xor(acc[j], s);
  int j = lane & 15;
  float tr = 0.f, ti = 0.f;
#pragma unroll
  for (int t = 0; t < 16; ++t) {
    tr += acc[t] * Ar[t * 16 + j];
    ti += acc[t] * Ai[t * 16 + j];
  }
  float p = tr * tr + ti * ti;
  float ps = p;
#pragma unroll
  for (int s = 1; s < 16; s <<= 1) ps += __shfl_xor(ps, s);
  if (lane < 16) (side ? kp : qp)[row * 16 + lane] = p;
  if (lane == 0) (side ? fwk : fwq)[row] = 1.f / (1.f + __expf(-ps * (1.f / 16.f)));
}

// ---------- fuse (both sides in one launch) ----------
struct FuseP {
  const float* lin; const float* cl; const float* qp; const float* fw;
  const float* mb; unsigned short* ext; float sA, sB;
};
struct Fuse2 { FuseP s[2]; };
__global__ __launch_bounds__(512) void fuse_k(Fuse2 fp) {
  FuseP P = fp.s[blockIdx.y];
  int row = blockIdx.x;
  int b = row >> 9, i = row & 511;
  int d = threadIdx.x;
  const float* qpr = P.qp + row * 16;
  float fwv = P.fw[row];
  float qout = 0.f;
#pragma unroll
  for (int t = 0; t < 16; ++t) qout += qpr[t] * P.mb[t * 512 + d];
  float qq = fwv * qout + (1.f - fwv) * tanhf(P.cl[(long long)row * 512 + d]);
  float val = (0.7f * P.lin[(long long)row * 512 + d] + 0.3f * qq) * P.sA;
  int h = d >> 6, dd = d & 63;
  P.ext[(((long long)(b * 8 + h)) * 512 + i) * 96 + dd] = f2b(val);
  if (d < 128) {
    int h2 = d >> 4, j = d & 15;
    P.ext[(((long long)(b * 8 + h2)) * 512 + i) * 96 + 64 + j] = f2b(P.sB * qpr[j]);
  } else if (d < 256) {
    int t2 = d - 128;
    int h2 = t2 >> 4, j = t2 & 15;
    P.ext[(((long long)(b * 8 + h2)) * 512 + i) * 96 + 80 + j] = 0;
  }
}

// ---------- wave-per-row layernorm ----------
__global__ __launch_bounds__(256) void ln_k(const float* __restrict__ y,
    const float* __restrict__ g, const float* __restrict__ be,
    float* __restrict__ xo, unsigned short* __restrict__ xb, float* __restrict__ xo2) {
  int wv = threadIdx.x >> 6, lane = threadIdx.x & 63;
  long long row = (long long)blockIdx.x * 4 + wv;
  const float* yr = y + row * 512 + lane * 8;
  f32x4 a = *(const f32x4*)yr, b = *(const f32x4*)(yr + 4);
  float s = a[0] + a[1] + a[2] + a[3] + b[0] + b[1] + b[2] + b[3];
#pragma unroll
  for (int m = 32; m; m >>= 1) s += __shfl_xor(s, m);
  float mu = s * (1.f / 512.f);
  float d[8], vs = 0.f;
#pragma unroll
  for (int j = 0; j < 4; ++j) { d[j] = a[j] - mu; vs += d[j] * d[j]; }
#pragma unroll
  for (int j = 0; j < 4; ++j) { d[4 + j] = b[j] - mu; vs += d[4 + j] * d[4 + j]; }
#pragma unroll
  for (int m = 32; m; m >>= 1) vs += __shfl_xor(vs, m);
  float rstd = rsqrtf(vs * (1.f / 512.f) + 1e-5f);
  f32x4 g0 = *(const f32x4*)(g + lane * 8), g1 = *(const f32x4*)(g + lane * 8 + 4);
  f32x4 b0 = *(const f32x4*)(be + lane * 8), b1 = *(const f32x4*)(be + lane * 8 + 4);
  f32x4 o0, o1; s16x8 ob;
#pragma unroll
  for (int j = 0; j < 4; ++j) { o0[j] = d[j] * rstd * g0[j] + b0[j]; ob[j] = (short)f2b(o0[j]); }
#pragma unroll
  for (int j = 0; j < 4; ++j) { o1[j] = d[4 + j] * rstd * g1[j] + b1[j]; ob[4 + j] = (short)f2b(o1[j]); }
  float* xr = xo + row * 512 + lane * 8;
  *(f32x4*)xr = o0; *(f32x4*)(xr + 4) = o1;
  *(s16x8*)(xb + row * 512 + lane * 8) = ob;
  if (xo2) {
    float* x2 = xo2 + row * 512 + lane * 8;
    *(f32x4*)x2 = o0; *(f32x4*)(x2 + 4) = o1;
  }
}

// ---------- pooled heads (partial sums then final) ----------
__global__ __launch_bounds__(512) void poolpart_k(const float* __restrict__ x,
                                                   float* __restrict__ part) {
  int b = blockIdx.x, ch = blockIdx.y, d = threadIdx.x;
  float s = 0.f;
  for (int r = 0; r < 64; ++r) s += x[((long long)(b * 512 + ch * 64 + r)) * 512 + d];
  part[(b * 8 + ch) * 512 + d] = s;
}
__global__ __launch_bounds__(512) void head_k(const float* __restrict__ part,
    const float* __restrict__ Ws, const float* __restrict__ bs,
    const float* __restrict__ Wd, const float* __restrict__ bd,
    const float* __restrict__ We, const float* __restrict__ be, float* __restrict__ out) {
  __shared__ float pooled[512];
  __shared__ float dl[5];
  int b = blockIdx.x, d = threadIdx.x;
  float s = 0.f;
  for (int t = 0; t < 8; ++t) s += part[(b * 8 + t) * 512 + d];
  pooled[d] = s * (1.f / 512.f);
  __syncthreads();
  if (d < 64) {
    float a = bs[d];
    for (int t = 0; t < 512; ++t) a += pooled[t] * Ws[t * 64 + d];
    out[b * 64 + d] = 1.f / (1.f + __expf(-a));
  } else if (d < 69) {
    int j = d - 64;
    float a = bd[j];
    for (int t = 0; t < 512; ++t) a += pooled[t] * Wd[t * 5 + j];
    dl[j] = a;
  } else if (d == 69) {
    float a = be[0];
    for (int t = 0; t < 512; ++t) a += pooled[t] * We[t];
    out[276 + b] = 1.f / (1.f + __expf(-a));
  }
  __syncthreads();
  if (d < 5) {
    float mx = dl[0];
    for (int j = 1; j < 5; ++j) mx = fmaxf(mx, dl[j]);
    float sm = 0.f;
    for (int j = 0; j < 5; ++j) sm += __expf(dl[j] - mx);
    out[256 + b * 5 + d] = __expf(dl[d] - mx) / sm;
  }
}

// ---------- host ----------
extern "C" void kernel_launch(void* const* d_in, const int* in_sizes, int n_in,
                              void* d_out, int out_size, void* d_ws, size_t ws_size,
                              hipStream_t stream) {
  (void)in_sizes; (void)n_in; (void)out_size; (void)ws_size;
  const int*   text     = (const int*)  d_in[0];
  const float* visual   = (const float*)d_in[1];
  const float* temporal = (const float*)d_in[2];
  const float* embedw   = (const float*)d_in[3];
  const float* Wvis  = (const float*)d_in[4];  const float* bvis  = (const float*)d_in[5];
  const float* Wtemp = (const float*)d_in[6];  const float* btemp = (const float*)d_in[7];
  const float* Wq = (const float*)d_in[8];   const float* bq = (const float*)d_in[9];
  const float* Wk = (const float*)d_in[10];  const float* bk = (const float*)d_in[11];
  const float* Wv = (const float*)d_in[12];  const float* bv = (const float*)d_in[13];
  const float* Wo = (const float*)d_in[14];  const float* bo = (const float*)d_in[15];
  const float* qW = (const float*)d_in[16];  const float* qb = (const float*)d_in[17];
  const float* q_qwr = (const float*)d_in[18]; const float* q_qwi = (const float*)d_in[19];
  const float* q_sg  = (const float*)d_in[20]; const float* q_em  = (const float*)d_in[21];
  const float* q_mb  = (const float*)d_in[22];
  const float* kW = (const float*)d_in[23];  const float* kb = (const float*)d_in[24];
  const float* k_qwr = (const float*)d_in[25]; const float* k_qwi = (const float*)d_in[26];
  const float* k_sg  = (const float*)d_in[27]; const float* k_em  = (const float*)d_in[28];
  const float* k_mb  = (const float*)d_in[29];
  const float* ln_g = (const float*)d_in[30]; const float* ln_b = (const float*)d_in[31];
  const float* Ws = (const float*)d_in[32];  const float* bs_ = (const float*)d_in[33];
  const float* Wd = (const float*)d_in[34];  const float* bd = (const float*)d_in[35];
  const float* We = (const float*)d_in[36];  const float* be = (const float*)d_in[37];
  float* out = (float*)d_out;

  char* w = (char*)d_ws;
  auto alloc = [&](size_t bytes) {
    char* p = w;
    w += (bytes + 255) & ~(size_t)255;
    return p;
  };
  float* ws_x   = (float*)alloc(2048ll * 512 * 4);
  unsigned short* ws_xb = (unsigned short*)alloc(2048ll * 512 * 2);
  unsigned short* ws_Wt = (unsigned short*)alloc(36ll * 262144 * 2);
  float* ws_bias = (float*)alloc(6ll * 6 * 512 * 4);
  float* ws_ArAi = (float*)alloc(6ll * 1024 * 4);
  float* ws_proj = (float*)alloc(4ll * 512 * 4);
  float* ws_vp   = (float*)alloc(4ll * 32 * 512 * 4);
  float* ws_Q    = (float*)alloc(2048ll * 512 * 4);
  float* ws_K    = (float*)alloc(2048ll * 512 * 4);
  float* ws_Cq   = (float*)alloc(2048ll * 512 * 4);
  float* ws_Ck   = (float*)alloc(2048ll * 512 * 4);
  float* ws_qp   = (float*)alloc(2048ll * 16 * 4);
  float* ws_kp   = (float*)alloc(2048ll * 16 * 4);
  float* ws_fwq  = (float*)alloc(2048ll * 4);
  float* ws_fwk  = (float*)alloc(2048ll * 4);
  unsigned short* ws_Vt   = (unsigned short*)alloc(2048ll * 512 * 2);
  unsigned short* ws_Qext = (unsigned short*)alloc(4ll * 8 * 512 * 96 * 2);
  unsigned short* ws_Kext = (unsigned short*)alloc(4ll * 8 * 512 * 96 * 2);
  unsigned short* ws_ctx  = (unsigned short*)alloc(2048ll * 512 * 2);
  float* ws_y    = (float*)alloc(2048ll * 512 * 4);

  Ptr6 wsrc = {{Wq, Wk, Wv, qW, kW, Wo}};
  wt_k<<<dim3(16, 16, 36), dim3(32, 8), 0, stream>>>(wsrc, ws_Wt);
  Ptr6 bsrc = {{bq, bk, bv, qb, kb, bo}};
  prep_k<<<dim3(6), dim3(256), 0, stream>>>(bsrc, q_qwr, q_qwi, q_em, k_qwr, k_qwi, k_em,
                                            ws_bias, ws_ArAi);
  vispart_k<<<dim3(4, 32), dim3(512), 0, stream>>>(visual, Wvis, ws_vp);
  projsum_k<<<dim3(4), dim3(512), 0, stream>>>(ws_vp, bvis, temporal, Wtemp, btemp, ws_proj);
  embed_k<<<dim3(2048), dim3(512), 0, stream>>>(text, embedw, ws_proj, ws_x, ws_xb);

  const long long ATTN_OFF = 280ll + 1048576ll;
  for (int l = 0; l < 6; ++l) {
    const unsigned short* WtL = ws_Wt + (long long)l * 6 * 262144;
    const float* biasL = ws_bias + (long long)l * 6 * 512;

    Outs5 o5{};
    o5.o[0] = { ws_Q, MODE_F32 };  o5.o[1] = { ws_K, MODE_F32 };
    o5.o[2] = { ws_Vt, MODE_VT };  o5.o[3] = { ws_Cq, MODE_F32 };
    o5.o[4] = { ws_Ck, MODE_F32 };
    gemm_nt<128, 128, 2, 2><<<dim3(16, 4, 5), 256, 0, stream>>>(
        ws_xb, 512, 0ll, WtL, 512, 262144ll, biasL, 512, 1, o5, nullptr, 512);

    quantum_k<<<dim3(2048, 2), 64, 0, stream>>>(ws_x, q_sg + l * 8192, k_sg + l * 8192,
        ws_ArAi + l * 1024, ws_qp, ws_kp, ws_fwq, ws_fwk);

    Fuse2 f2{};
    f2.s[0] = { ws_Q, ws_Cq, ws_qp, ws_fwq, q_mb + l * 8192, ws_Qext, 0.125f, 0.1f };
    f2.s[1] = { ws_K, ws_Ck, ws_kp, ws_fwk, k_mb + l * 8192, ws_Kext, 1.0f, 1.0f };
    fuse_k<<<dim3(2048, 2), dim3(512), 0, stream>>>(f2);

    fused_attn<<<dim3(32, 8), 256, 0, stream>>>(
        ws_Qext, ws_Kext, ws_Vt, out + ATTN_OFF + (long long)l * 8388608, ws_ctx);

    Outs5 oy{};
    oy.o[0] = { ws_y, MODE_Y };
    gemm_nt<64, 64, 2, 2><<<dim3(32, 8, 1), 256, 0, stream>>>(
        ws_ctx, 512, 0ll, WtL + 5 * 262144, 512, 0ll, biasL + 5 * 512, 0, 0, oy, ws_x, 512);

    ln_k<<<dim3(512), dim3(256), 0, stream>>>(ws_y, ln_g + l * 512, ln_b + l * 512,
        ws_x, ws_xb, (l == 5) ? (out + 280) : nullptr);
  }

  poolpart_k<<<dim3(4, 8), dim3(512), 0, stream>>>(ws_x, ws_vp);
  head_k<<<dim3(4), dim3(512), 0, stream>>>(ws_vp, Ws, bs_, Wd, bd, We, be, out);
}